// Round 1
// baseline (11.781 us; speedup 1.0000x reference)
//
#include <hip/hip_runtime.h>

// Problem constants (match reference)
constexpr int GROUPS = 256;
constexpr int K = 19;
constexpr int L = 1000;
constexpr int B = 256;
constexpr int T = L - K + 1;   // 982 valid conv positions

// out[b,g] = sum_{c,k} w[g,c,k] * (S[b,c,k] + S[b,3-c,K-1-k]) + 2*T*bias[g]
// where S[b,c,k] = sum_{l=k}^{k+T-1} x[b,c,l]
__global__ __launch_bounds__(256) void pwm_sum_kernel(
    const float* __restrict__ x,     // (B, 4, L)
    const float* __restrict__ w,     // (GROUPS, 4, K)
    const float* __restrict__ bias,  // (GROUPS,)
    float* __restrict__ out)         // (B, GROUPS)
{
    const int b    = blockIdx.x;
    const int tid  = threadIdx.x;
    const int wave = tid >> 6;   // 0..3 -> channel index
    const int lane = tid & 63;

    __shared__ float S_lds[4 * K];   // window sums per (channel, k)
    __shared__ float Q_lds[4 * K];   // fwd + revcomp combined

    // ---- Phase 1: per-channel full reduction (one wave per channel) ----
    const float* xc = x + (size_t)b * 4 * L + (size_t)wave * L;
    float acc = 0.f;
    for (int l = lane; l < L; l += 64) acc += xc[l];
    // 64-lane butterfly reduction -> every lane holds the full channel sum
    #pragma unroll
    for (int off = 32; off > 0; off >>= 1)
        acc += __shfl_xor(acc, off, 64);

    // ---- window sums: S[k] = full - head(k) - tail(18-k) ----
    if (lane < K) {
        float head = 0.f;
        for (int l = 0; l < lane; ++l) head += xc[l];          // first `lane` elems
        float tail = 0.f;
        for (int l = lane + T; l < L; ++l) tail += xc[l];      // last `K-1-lane` elems
        S_lds[wave * K + lane] = acc - head - tail;
    }
    __syncthreads();

    // ---- Phase 2: combine forward + reverse-complement ----
    if (tid < 4 * K) {
        const int c = tid / K;
        const int k = tid % K;
        Q_lds[tid] = S_lds[tid] + S_lds[(3 - c) * K + (K - 1 - k)];
    }
    __syncthreads();

    // ---- Phase 3: one output per thread: dot(Q, w[g]) ----
    const int g = tid;  // GROUPS == blockDim.x == 256
    // w row is 76 floats = 304 bytes, 16B-aligned -> 19 float4 loads
    const float4* wg = reinterpret_cast<const float4*>(w + (size_t)g * 4 * K);
    float o = 0.f;
    #pragma unroll
    for (int i = 0; i < 19; ++i) {
        const float4 wv = wg[i];
        o += wv.x * Q_lds[4 * i + 0]
           + wv.y * Q_lds[4 * i + 1]
           + wv.z * Q_lds[4 * i + 2]
           + wv.w * Q_lds[4 * i + 3];
    }
    o += bias[g] * (2.0f * (float)T);

    out[(size_t)b * GROUPS + g] = o;
}

extern "C" void kernel_launch(void* const* d_in, const int* in_sizes, int n_in,
                              void* d_out, int out_size, void* d_ws, size_t ws_size,
                              hipStream_t stream) {
    const float* x    = (const float*)d_in[0];  // (B,4,L) f32
    const float* w    = (const float*)d_in[1];  // (GROUPS,4,K) f32
    const float* bias = (const float*)d_in[2];  // (GROUPS,) f32
    float* out        = (float*)d_out;          // (B,GROUPS) f32

    pwm_sum_kernel<<<B, 256, 0, stream>>>(x, w, bias, out);
}